// Round 1
// baseline (12902.608 us; speedup 1.0000x reference)
//
#include <hip/hip_runtime.h>
#include <hip/hip_bf16.h>

typedef unsigned short ushort_t;
typedef unsigned int uint_t;
typedef __attribute__((ext_vector_type(8))) short short8;
typedef __attribute__((ext_vector_type(4))) float f32x4;

// ---------------- workspace layout (bytes) ----------------
constexpr size_t OFF_WSFT = 0;                                   // bf16 [512][512]  WsfT[n][k] = W_sf[k][n], k<512
constexpr size_t OFF_WAFT = OFF_WSFT + 512*512*2;                // bf16 [512][512]
constexpr size_t OFF_WAST = OFF_WAFT + 512*512*2;                // bf16 [512][1024]
constexpr size_t OFF_WSST = OFF_WAST + 512*1024*2;               // bf16 [512][1024]
constexpr size_t OFF_WO1T = OFF_WSST + 512*1024*2;               // bf16 [512][1536]
constexpr size_t OFF_XTAB = OFF_WO1T + 512*1536*2;               // bf16 [600][512]  X = skill_embed[sk]+ans_embed[a]
constexpr size_t OFF_PRO  = OFF_XTAB + 600*512*2;                // bf16 [300][512]  skill_embed
constexpr size_t OFF_GAP  = OFF_PRO  + 300*512*2;                // f32  [200][512]  time_embed @ W_sf[512:] + b_sf
constexpr size_t OFF_CAF  = OFF_GAP  + 200*512*4;                // f32  [512]       time_embed[1] @ W_af[512:] + b_af
constexpr size_t OFF_AS32 = OFF_CAF  + 512*4;                    // f32  [2][512][512] all_state ping-pong
constexpr size_t OFF_ASBF = OFF_AS32 + 2*512*512*4;              // bf16 [2][512][512]
constexpr size_t OFF_LA32 = OFF_ASBF + 2*512*512*2;              // f32  [512][512]  gated last_all
constexpr size_t OFF_LABF = OFF_LA32 + 512*512*4;                // bf16
constexpr size_t OFF_LS32 = OFF_LABF + 512*512*2;                // f32  [512][512]  gated last_sk
constexpr size_t OFF_LSBF = OFF_LS32 + 512*512*4;                // bf16
constexpr size_t OFF_LT   = OFF_LSBF + 512*512*2;                // i32  [512][300]  last_time
constexpr size_t OFF_BAR  = OFF_LT   + 512*300*4;                // i32  [8][128]    group barrier counters
constexpr size_t OFF_SKB  = OFF_BAR  + 4096;                     // bf16 [512][199][512] skill_buf
constexpr size_t WS_NEED  = OFF_SKB  + (size_t)512*199*512*2;    // ~112 MB

__device__ __forceinline__ ushort_t f2bf(float f) {
  union { float f; uint_t u; } v; v.f = f;
  uint_t u = v.u;
  return (ushort_t)((u + 0x7FFFu + ((u >> 16) & 1u)) >> 16);
}
__device__ __forceinline__ float bf2f(ushort_t h) {
  union { uint_t u; float f; } v; v.u = ((uint_t)h) << 16;
  return v.f;
}

// ---------------- prologue ----------------
__global__ void rekt_prologue(const float* __restrict__ skill_embed, const float* __restrict__ ans_embed,
                              const float* __restrict__ time_embed, const float* __restrict__ ls_state,
                              const float* __restrict__ skill_state0,
                              const float* __restrict__ W_sf, const float* __restrict__ b_sf,
                              const float* __restrict__ W_af, const float* __restrict__ b_af,
                              const float* __restrict__ W_ss, const float* __restrict__ W_as,
                              const float* __restrict__ W_o1,
                              float* __restrict__ d_out, char* __restrict__ ws) {
  ushort_t* WsfT = (ushort_t*)(ws + OFF_WSFT);
  ushort_t* WafT = (ushort_t*)(ws + OFF_WAFT);
  ushort_t* WasT = (ushort_t*)(ws + OFF_WAST);
  ushort_t* WssT = (ushort_t*)(ws + OFF_WSST);
  ushort_t* Wo1T = (ushort_t*)(ws + OFF_WO1T);
  ushort_t* Xtab = (ushort_t*)(ws + OFF_XTAB);
  ushort_t* PROt = (ushort_t*)(ws + OFF_PRO);
  float*    GAP  = (float*)(ws + OFF_GAP);
  float*    CAF  = (float*)(ws + OFF_CAF);
  float*    AS32 = (float*)(ws + OFF_AS32);
  ushort_t* ASBF = (ushort_t*)(ws + OFF_ASBF);
  int*      LT   = (int*)(ws + OFF_LT);
  int*      BARp = (int*)(ws + OFF_BAR);
  ushort_t* SKB  = (ushort_t*)(ws + OFF_SKB);

  const size_t t0 = (size_t)blockIdx.x * blockDim.x + threadIdx.x;
  const size_t st = (size_t)gridDim.x * blockDim.x;

  for (size_t i = t0; i < 512*512; i += st) {
    int n = (int)(i >> 9), k = (int)(i & 511);
    WsfT[i] = f2bf(W_sf[(size_t)k*512 + n]);
    WafT[i] = f2bf(W_af[(size_t)k*512 + n]);
  }
  for (size_t i = t0; i < 512*1024; i += st) {
    int n = (int)(i >> 10), k = (int)(i & 1023);
    WasT[i] = f2bf(W_as[(size_t)k*512 + n]);
    WssT[i] = f2bf(W_ss[(size_t)k*512 + n]);
  }
  for (size_t i = t0; i < 512*1536; i += st) {
    int n = (int)(i / 1536), k = (int)(i % 1536);
    Wo1T[i] = f2bf(W_o1[(size_t)k*512 + n]);
  }
  for (size_t i = t0; i < 600*512; i += st) {
    int row = (int)(i >> 9), j = (int)(i & 511);
    int a = row / 300, sk = row % 300;
    Xtab[i] = f2bf(skill_embed[(size_t)sk*512 + j] + ans_embed[(size_t)a*512 + j]);
  }
  for (size_t i = t0; i < 300*512; i += st) PROt[i] = f2bf(skill_embed[i]);
  for (size_t i = t0; i < 200*512; i += st) {
    int t = (int)(i >> 9), n = (int)(i & 511);
    float acc = b_sf[n];
    for (int k = 0; k < 512; ++k) acc += time_embed[(size_t)t*512 + k] * W_sf[(size_t)(512 + k)*512 + n];
    GAP[i] = acc;
  }
  for (size_t i = t0; i < 512; i += st) {
    float acc = b_af[i];
    for (int k = 0; k < 512; ++k) acc += time_embed[512 + k] * W_af[(size_t)(512 + k)*512 + i];
    CAF[i] = acc;
  }
  for (size_t i = t0; i < 512*512; i += st) {
    float v = ls_state[i & 511];
    AS32[i] = v;
    ASBF[i] = f2bf(v);
  }
  for (size_t i = t0; i < 512*512; i += st) {
    size_t b = i >> 9, n = i & 511;
    SKB[(b*199)*512 + n] = f2bf(skill_state0[n]);   // only slot 0 is ever read before written
  }
  for (size_t i = t0; i < 512*300; i += st) LT[i] = 0;
  for (size_t i = t0; i < 512*199; i += st) d_out[i] = 0.f;
  for (size_t i = t0; i < 1024; i += st) BARp[i] = 0;
}

// ---------------- main scan kernel helpers ----------------
__device__ __forceinline__ void group_barrier(int* cnt, int target) {
  __syncthreads();
  if (threadIdx.x == 0) {
    __threadfence();
    __hip_atomic_fetch_add(cnt, 1, __ATOMIC_RELEASE, __HIP_MEMORY_SCOPE_AGENT);
    while (__hip_atomic_load(cnt, __ATOMIC_RELAXED, __HIP_MEMORY_SCOPE_AGENT) < target) {
      __builtin_amdgcn_s_sleep(1);
    }
    __threadfence();
  }
  __syncthreads();
}

// stage 64 rows x 512 bf16 into LDS tile [64][520]
__device__ __forceinline__ void stage_rows(short* At, const ushort_t* __restrict__ table,
                                           const int* rows, int b0) {
  for (int i = threadIdx.x; i < 4096; i += 512) {
    const int r = i >> 6, c = (i & 63) << 3;
    const int row = rows ? rows[r] : (b0 + r);
    const uint4 v = *reinterpret_cast<const uint4*>(table + (size_t)row * 512 + c);
    *reinterpret_cast<uint4*>(At + r * 520 + c) = v;
  }
}

// GEMM over one K=512 chunk staged in LDS.  Tile M=64 x N=(NF==1?32:64) per block, 8 waves.
// wave w: m-frag (w&3), n-group (w>>2).
template<int NF>
__device__ __forceinline__ void gemm_chunk(const short* At, const ushort_t* __restrict__ WT,
                                           int n0, int ld, int kk0, f32x4* acc) {
  const int tid = threadIdx.x;
  const int lane = tid & 63, w = tid >> 6;
  const int m0 = (w & 3) << 4;
  const int nb = n0 + (w >> 2) * (NF * 16);
  const short* ap = At + (m0 + (lane & 15)) * 520 + ((lane >> 4) << 3);
  const ushort_t* bp = WT + (size_t)(nb + (lane & 15)) * ld + kk0 + ((lane >> 4) << 3);
#pragma unroll 4
  for (int kk = 0; kk < 512; kk += 32) {
    const short8 a = *reinterpret_cast<const short8*>(ap + kk);
#pragma unroll
    for (int nf = 0; nf < NF; ++nf) {
      const short8 b = *reinterpret_cast<const short8*>(bp + (size_t)nf * 16 * ld + kk);
      acc[nf] = __builtin_amdgcn_mfma_f32_16x16x32_bf16(a, b, acc[nf], 0, 0, 0);
    }
  }
}

// ---------------- main scan ----------------
// grid = 256 blocks (8 groups x 32), block = 512 threads (8 waves).
__global__ __launch_bounds__(512, 1) void rekt_main(
    const int* __restrict__ next_skill, const int* __restrict__ next_ans,
    const float* __restrict__ b_o1, const float* __restrict__ w_o2,
    const float* __restrict__ b_as, const float* __restrict__ b_ss,
    float* __restrict__ d_out, char* __restrict__ ws) {

  const ushort_t* WsfT = (const ushort_t*)(ws + OFF_WSFT);
  const ushort_t* WafT = (const ushort_t*)(ws + OFF_WAFT);
  const ushort_t* WasT = (const ushort_t*)(ws + OFF_WAST);
  const ushort_t* WssT = (const ushort_t*)(ws + OFF_WSST);
  const ushort_t* Wo1T = (const ushort_t*)(ws + OFF_WO1T);
  const ushort_t* Xtab = (const ushort_t*)(ws + OFF_XTAB);
  const ushort_t* PROt = (const ushort_t*)(ws + OFF_PRO);
  const float*    GAP  = (const float*)(ws + OFF_GAP);
  const float*    CAF  = (const float*)(ws + OFF_CAF);
  float*    AS32 = (float*)(ws + OFF_AS32);
  ushort_t* ASBF = (ushort_t*)(ws + OFF_ASBF);
  float*    LA32 = (float*)(ws + OFF_LA32);
  ushort_t* LABF = (ushort_t*)(ws + OFF_LABF);
  float*    LS32 = (float*)(ws + OFF_LS32);
  ushort_t* LSBF = (ushort_t*)(ws + OFF_LSBF);
  int*      LT   = (int*)(ws + OFF_LT);
  int*      BARp = (int*)(ws + OFF_BAR);
  ushort_t* SKB  = (ushort_t*)(ws + OFF_SKB);

  __shared__ __align__(16) short At[64 * 520];
  __shared__ int tl_s[64], gap_s[64], sk_s[64], xr_s[64], skrow_s[64];

  const int tid = threadIdx.x;
  const int lane = tid & 63, w = tid >> 6;
  const int bid = blockIdx.x;
  const int g = bid >> 5, lid = bid & 31;
  const int b0 = g << 6;
  int* cnt = BARp + g * 128;

  const int m0 = (w & 3) << 4;
  const int rb = m0 + ((lane >> 4) << 2);   // row base of the 4 acc regs
  int it = 0;

  for (int s = 0; s < 199; ++s) {
    const int cur = s & 1, nxt = cur ^ 1;

    if (tid < 64) {
      const int b = b0 + tid;
      const int sk = next_skill[b * 199 + s];
      const int tl = LT[b * 300 + sk];
      tl_s[tid] = tl;
      gap_s[tid] = s - tl;
      sk_s[tid] = sk;
      xr_s[tid] = next_ans[b * 199 + s] * 300 + sk;
      skrow_s[tid] = b * 199 + tl;
    }
    __syncthreads();

    // ================= PHASE A =================
    if (lid < 16) {
      // A1: F = gather(SKB) @ WsfT  -> LS = SKg * sigmoid(F + GAP[gap])
      stage_rows(At, SKB, skrow_s, 0);
      __syncthreads();
      const int n0 = lid << 5;
      f32x4 acc = {0.f, 0.f, 0.f, 0.f};
      gemm_chunk<1>(At, WsfT, n0, 512, 0, &acc);
      const int nc = n0 + ((w >> 2) << 4) + (lane & 15);
#pragma unroll
      for (int q = 0; q < 4; ++q) {
        const int r = rb + q;
        const int b = b0 + r;
        const float F = acc[q] + GAP[(size_t)gap_s[r] * 512 + nc];
        const float sg = 1.f / (1.f + __expf(-F));
        const float skg = bf2f(SKB[(size_t)skrow_s[r] * 512 + nc]);
        const float ls = skg * sg;
        LS32[(size_t)b * 512 + nc] = ls;
        LSBF[(size_t)b * 512 + nc] = f2bf(ls);
      }
    } else {
      // A2: G = AS @ WafT -> LA = AS * sigmoid(G + CAF)
      stage_rows(At, ASBF + (size_t)cur * 512 * 512, nullptr, b0);
      __syncthreads();
      const int n0 = (lid - 16) << 5;
      f32x4 acc = {0.f, 0.f, 0.f, 0.f};
      gemm_chunk<1>(At, WafT, n0, 512, 0, &acc);
      const int nc = n0 + ((w >> 2) << 4) + (lane & 15);
#pragma unroll
      for (int q = 0; q < 4; ++q) {
        const int b = b0 + rb + q;
        const float G = acc[q] + CAF[nc];
        const float sg = 1.f / (1.f + __expf(-G));
        const float as = AS32[(size_t)cur * 262144 + (size_t)b * 512 + nc];
        const float la = as * sg;
        LA32[(size_t)b * 512 + nc] = la;
        LABF[(size_t)b * 512 + nc] = f2bf(la);
      }
    }
    group_barrier(cnt, (++it) * 32);

    // ================= PHASE B =================
    if (lid < 16) {
      // H: h = relu([LA|LS|PRO] @ Wo1T + b_o1); P += h . w_o2
      const int n0 = lid << 5;
      f32x4 acc = {0.f, 0.f, 0.f, 0.f};
      stage_rows(At, LABF, nullptr, b0); __syncthreads();
      gemm_chunk<1>(At, Wo1T, n0, 1536, 0, &acc); __syncthreads();
      stage_rows(At, LSBF, nullptr, b0); __syncthreads();
      gemm_chunk<1>(At, Wo1T, n0, 1536, 512, &acc); __syncthreads();
      stage_rows(At, PROt, sk_s, 0); __syncthreads();
      gemm_chunk<1>(At, Wo1T, n0, 1536, 1024, &acc);
      const int nc = n0 + ((w >> 2) << 4) + (lane & 15);
      float pv[4];
#pragma unroll
      for (int q = 0; q < 4; ++q) {
        float h = acc[q] + b_o1[nc];
        h = fmaxf(h, 0.f);
        pv[q] = h * w_o2[nc];
      }
#pragma unroll
      for (int msk = 1; msk < 16; msk <<= 1) {
#pragma unroll
        for (int q = 0; q < 4; ++q) pv[q] += __shfl_xor(pv[q], msk, 64);
      }
      if ((lane & 15) == 0) {
#pragma unroll
        for (int q = 0; q < 4; ++q) atomicAdd(&d_out[(size_t)(b0 + rb + q) * 199 + s], pv[q]);
      }
    } else if (lid < 24) {
      // NA: AS[nxt] = LA + tanh([LA|X] @ WasT + b_as)
      const int n0 = (lid - 16) << 6;
      f32x4 acc[2] = {{0.f,0.f,0.f,0.f},{0.f,0.f,0.f,0.f}};
      stage_rows(At, LABF, nullptr, b0); __syncthreads();
      gemm_chunk<2>(At, WasT, n0, 1024, 0, acc); __syncthreads();
      stage_rows(At, Xtab, xr_s, 0); __syncthreads();
      gemm_chunk<2>(At, WasT, n0, 1024, 512, acc);
#pragma unroll
      for (int nf = 0; nf < 2; ++nf) {
        const int nc = n0 + ((w >> 2) << 5) + (nf << 4) + (lane & 15);
#pragma unroll
        for (int q = 0; q < 4; ++q) {
          const int b = b0 + rb + q;
          float x = acc[nf][q] + b_as[nc];
          x = fminf(fmaxf(x, -12.f), 12.f);
          const float e = __expf(2.f * x);
          const float th = (e - 1.f) / (e + 1.f);
          const float o = LA32[(size_t)b * 512 + nc] + th;
          AS32[(size_t)nxt * 262144 + (size_t)b * 512 + nc] = o;
          ASBF[(size_t)nxt * 262144 + (size_t)b * 512 + nc] = f2bf(o);
        }
      }
    } else {
      // NS: SKB[b][s] = LS + tanh([LS|X] @ WssT + b_ss)
      const int n0 = (lid - 24) << 6;
      f32x4 acc[2] = {{0.f,0.f,0.f,0.f},{0.f,0.f,0.f,0.f}};
      stage_rows(At, LSBF, nullptr, b0); __syncthreads();
      gemm_chunk<2>(At, WssT, n0, 1024, 0, acc); __syncthreads();
      stage_rows(At, Xtab, xr_s, 0); __syncthreads();
      gemm_chunk<2>(At, WssT, n0, 1024, 512, acc);
#pragma unroll
      for (int nf = 0; nf < 2; ++nf) {
        const int nc = n0 + ((w >> 2) << 5) + (nf << 4) + (lane & 15);
#pragma unroll
        for (int q = 0; q < 4; ++q) {
          const int b = b0 + rb + q;
          float x = acc[nf][q] + b_ss[nc];
          x = fminf(fmaxf(x, -12.f), 12.f);
          const float e = __expf(2.f * x);
          const float th = (e - 1.f) / (e + 1.f);
          const float o = LS32[(size_t)b * 512 + nc] + th;
          SKB[((size_t)b * 199 + s) * 512 + nc] = f2bf(o);
        }
      }
    }
    if (lid == 16 && tid < 64) LT[(b0 + tid) * 300 + sk_s[tid]] = s;
    group_barrier(cnt, (++it) * 32);
  }
}

// ---------------- tail: P = sigmoid(P + b_o2) ----------------
__global__ void rekt_sigmoid(float* __restrict__ d_out, const float* __restrict__ b_o2) {
  const int i = blockIdx.x * blockDim.x + threadIdx.x;
  if (i < 512 * 199) {
    const float v = d_out[i] + b_o2[0];
    d_out[i] = 1.f / (1.f + __expf(-v));
  }
}

extern "C" void kernel_launch(void* const* d_in, const int* in_sizes, int n_in,
                              void* d_out, int out_size, void* d_ws, size_t ws_size,
                              hipStream_t stream) {
  const int*   next_skill   = (const int*)d_in[4];
  const int*   next_ans     = (const int*)d_in[5];
  const float* skill_embed  = (const float*)d_in[6];
  const float* ans_embed    = (const float*)d_in[7];
  const float* time_embed   = (const float*)d_in[8];
  const float* ls_state     = (const float*)d_in[9];
  const float* skill_state0 = (const float*)d_in[10];
  const float* W_sf = (const float*)d_in[11];
  const float* b_sf = (const float*)d_in[12];
  const float* W_af = (const float*)d_in[13];
  const float* b_af = (const float*)d_in[14];
  const float* W_ss = (const float*)d_in[15];
  const float* b_ss = (const float*)d_in[16];
  const float* W_as = (const float*)d_in[17];
  const float* b_as = (const float*)d_in[18];
  const float* W_o1 = (const float*)d_in[19];
  const float* b_o1 = (const float*)d_in[20];
  const float* W_o2 = (const float*)d_in[21];
  const float* b_o2 = (const float*)d_in[22];
  float* out = (float*)d_out;
  char*  ws  = (char*)d_ws;

  if (ws_size < WS_NEED) return;  // fail loudly (output stays poisoned)

  rekt_prologue<<<dim3(1024), dim3(256), 0, stream>>>(
      skill_embed, ans_embed, time_embed, ls_state, skill_state0,
      W_sf, b_sf, W_af, b_af, W_ss, W_as, W_o1, out, ws);

  rekt_main<<<dim3(256), dim3(512), 0, stream>>>(
      next_skill, next_ans, b_o1, W_o2, b_as, b_ss, out, ws);

  rekt_sigmoid<<<dim3((512 * 199 + 255) / 256), dim3(256), 0, stream>>>(out, b_o2);
}